// Round 1
// 1057.394 us; speedup vs baseline: 1.4678x; 1.4678x over previous
//
#include <hip/hip_runtime.h>
#include <hip/hip_bf16.h>

typedef __attribute__((ext_vector_type(8))) short short8;
typedef __attribute__((ext_vector_type(4))) short s16x4;
typedef __attribute__((ext_vector_type(4))) float f32x4;

#define D_H   224
#define D_W   224
#define D_HW  50176
#define SCALE 0.17677669529663687f  // 32^-0.5

static __device__ __forceinline__ short f2s(float v) {
    union { __hip_bfloat16 b; short s; } u; u.b = __float2bfloat16(v); return u.s;
}
static __device__ __forceinline__ float s2f(short s) {
    union { short s; __hip_bfloat16 b; } u; u.s = s; return __bfloat162float(u.b);
}

#define MFMA(a, b, c) __builtin_amdgcn_mfma_f32_16x16x32_bf16((a), (b), (c), 0, 0, 0)

// ---------------------------------------------------------------------------
// K1: one block per window.
//   - register softmax fused into S-epilogue (shfl_xor row reduce)
//   - QKV 3 chunks of 96 outputs, proj 1 chunk of 96 (float4 staging)
//   - hoisted A-frags, parallel LN, precomputed bias/mask indices
//   LDS ~75.5 KB -> 2 blocks/CU
// ---------------------------------------------------------------------------
__global__ __launch_bounds__(256) void k_attn(
    const float* __restrict__ x, const float* __restrict__ n1g, const float* __restrict__ n1b,
    const float* __restrict__ qkvw, const float* __restrict__ qkvb, const float* __restrict__ relt,
    const float* __restrict__ projw, const float* __restrict__ projb, float* __restrict__ y)
{
    __shared__ short qk[64][200];                       // Q(0..95 pre-scaled) K(96..191); PV out -> Q cols
    __shared__ short vt[96][72];                        // V d-major
    __shared__ __align__(16) char region[64*104*2 + 96*104*2];
    short (*xs)[104] = (short(*)[104])region;           // normalized input tokens
    short (*wb)[104] = (short(*)[104])(region + 64*104*2);  // weight chunk
    short (*ps)[72]  = (short(*)[72])region;            // P matrix (aliases xs, dead after QKV)
    __shared__ int   cnt_s[64];
    __shared__ float mean_s[64], rstd_s[64];
    __shared__ float relt_s[507];

    const int tid  = threadIdx.x;
    const int wave = tid >> 6, lane = tid & 63;
    const int l16  = lane & 15, q8 = (lane >> 4) * 8, q4 = (lane >> 4) * 4;
    const int t0   = wave * 16;

    const int wi = blockIdx.x;
    const int b  = wi >> 10, nw = wi & 1023;
    const int wh = nw >> 5, ww = nw & 31;
    const bool edge = (wh == 31) || (ww == 31);     // only edge windows straddle mask regions

    for (int i = tid; i < 507; i += 256) relt_s[i] = relt[i];
    if (tid < 64) {
        int t = (tid < 49) ? tid : 48;
        int r = t / 7, c = t - r * 7;
        int sh = wh * 7 + r, sw = ww * 7 + c;
        int rh = (sh < 217) ? 0 : ((sh < 221) ? 1 : 2);
        int rw = (sw < 217) ? 0 : ((sw < 221) ? 1 : 2);
        cnt_s[tid] = rh * 3 + rw;
    }
    // ---- gather: token = lane, each wave covers 24 channels, short4 LDS writes ----
    {
        int t = lane;
        int r = t / 7, cc = t - r * 7;
        int hh = wh * 7 + r + 3;  if (hh >= D_H) hh -= D_H;
        int w2 = ww * 7 + cc + 3; if (w2 >= D_W) w2 -= D_W;
        int off0 = (b * 96) * D_HW + hh * D_W + w2;
#pragma unroll
        for (int n = 0; n < 6; n++) {
            int c0 = wave * 24 + n * 4;
            s16x4 v4 = {0, 0, 0, 0};
            if (t < 49) {
                v4[0] = f2s(x[off0 + (c0 + 0) * D_HW]);
                v4[1] = f2s(x[off0 + (c0 + 1) * D_HW]);
                v4[2] = f2s(x[off0 + (c0 + 2) * D_HW]);
                v4[3] = f2s(x[off0 + (c0 + 3) * D_HW]);
            }
            *(s16x4*)&xs[t][c0] = v4;               // rows 49..63 zeroed
        }
    }
    __syncthreads();

    // ---- LayerNorm1: 4 lanes per token ----
    {
        int t = tid >> 2, p = tid & 3;
        if (t < 49) {
            float s = 0.f, s2 = 0.f;
#pragma unroll
            for (int i = 0; i < 6; i++) {
                s16x4 v4 = *(const s16x4*)&xs[t][p * 24 + i * 4];
#pragma unroll
                for (int j = 0; j < 4; j++) { float v = s2f(v4[j]); s += v; s2 += v * v; }
            }
            s += __shfl_xor(s, 1); s2 += __shfl_xor(s2, 1);
            s += __shfl_xor(s, 2); s2 += __shfl_xor(s2, 2);
            if (p == 0) {
                float m = s * (1.f / 96.f);
                float var = s2 * (1.f / 96.f) - m * m;
                mean_s[t] = m; rstd_s[t] = rsqrtf(var + 1e-5f);
            }
        }
    }
    __syncthreads();
    for (int idx = tid; idx < 49 * 24; idx += 256) {
        int t = idx / 24, qc = idx - t * 24;
        s16x4 v4 = *(const s16x4*)&xs[t][qc * 4];
        f32x4 g  = *(const f32x4*)&n1g[qc * 4];
        f32x4 bb = *(const f32x4*)&n1b[qc * 4];
        float m = mean_s[t], rs = rstd_s[t];
#pragma unroll
        for (int j = 0; j < 4; j++) v4[j] = f2s((s2f(v4[j]) - m) * rs * g[j] + bb[j]);
        *(s16x4*)&xs[t][qc * 4] = v4;
    }
    __syncthreads();

    // ---- hoisted A-frags (chunk-invariant) ----
    short8 a0 = *(const short8*)&xs[t0 + l16][q8];
    short8 a1 = *(const short8*)&xs[t0 + l16][32 + q8];
    short8 a2 = *(const short8*)&xs[t0 + l16][64 + q8];

    // ---- QKV: 3 chunks of 96 output channels ----
#pragma unroll
    for (int jc = 0; jc < 3; jc++) {
        __syncthreads();
#pragma unroll
        for (int k = 0; k < 9; k++) {
            int i = tid + k * 256;                  // < 2304
            int j = i / 24, qc = i - j * 24;
            f32x4 w4 = *(const f32x4*)&qkvw[(jc * 96 + j) * 96 + qc * 4];
            s16x4 s4;
#pragma unroll
            for (int jj = 0; jj < 4; jj++) s4[jj] = f2s(w4[jj]);
            *(s16x4*)&wb[j][qc * 4] = s4;
        }
        __syncthreads();
#pragma unroll
        for (int nt = 0; nt < 6; nt++) {
            f32x4 acc = {0.f, 0.f, 0.f, 0.f};
            acc = MFMA(a0, *(const short8*)&wb[nt * 16 + l16][q8],      acc);
            acc = MFMA(a1, *(const short8*)&wb[nt * 16 + l16][32 + q8], acc);
            acc = MFMA(a2, *(const short8*)&wb[nt * 16 + l16][64 + q8], acc);
            int j = nt * 16 + l16;
            float bias = qkvb[jc * 96 + j];
#pragma unroll
            for (int r = 0; r < 4; r++) {
                int t = t0 + q4 + r;
                float v = acc[r] + bias;
                if (jc == 0)      qk[t][j]      = f2s(v * SCALE);
                else if (jc == 1) qk[t][96 + j] = f2s(v);
                else              vt[j][t]      = f2s(v);
            }
        }
    }

    // ---- per-lane precompute for S epilogue (head-invariant) ----
    int   rix[4][4];     // relt index * 3
    float msk[4][4];     // 0 or -100
#pragma unroll
    for (int nt = 0; nt < 4; nt++) {
        int m  = nt * 16 + l16;
        int mm = (m < 49) ? m : 48;
        int r2 = mm / 7, c2 = mm - r2 * 7;
        int cm = cnt_s[m];
#pragma unroll
        for (int r = 0; r < 4; r++) {
            int n  = t0 + q4 + r;
            int nn = (n < 49) ? n : 48;
            int r1 = nn / 7, c1 = nn - r1 * 7;
            rix[nt][r] = ((r1 - r2 + 6) * 13 + (c1 - c2 + 6)) * 3;
            msk[nt][r] = (edge && (cnt_s[n] != cm)) ? -100.f : 0.f;
        }
    }
    const bool inval3 = (l16 != 0);                 // nt==3 col = 48+l16 invalid unless l16==0

    // ---- attention heads: S-MFMA + in-register softmax + PV ----
#pragma unroll
    for (int h = 0; h < 3; h++) {
        __syncthreads();                            // prev PV done reading ps / QKV writes done
        short8 aq = *(const short8*)&qk[t0 + l16][h * 32 + q8];
        f32x4 sv[4];
#pragma unroll
        for (int nt = 0; nt < 4; nt++) {
            f32x4 z = {0.f, 0.f, 0.f, 0.f};
            sv[nt] = MFMA(aq, *(const short8*)&qk[nt * 16 + l16][96 + h * 32 + q8], z);
        }
        float mx[4] = {-1e30f, -1e30f, -1e30f, -1e30f};
#pragma unroll
        for (int nt = 0; nt < 4; nt++) {
#pragma unroll
            for (int r = 0; r < 4; r++) {
                float v = sv[nt][r] + relt_s[rix[nt][r] + h] + msk[nt][r];
                if (nt == 3 && inval3) v = -1e30f;
                sv[nt][r] = v;
                mx[r] = fmaxf(mx[r], v);
            }
        }
#pragma unroll
        for (int d = 1; d < 16; d <<= 1) {
#pragma unroll
            for (int r = 0; r < 4; r++) mx[r] = fmaxf(mx[r], __shfl_xor(mx[r], d));
        }
        float sm[4] = {0.f, 0.f, 0.f, 0.f};
#pragma unroll
        for (int nt = 0; nt < 4; nt++) {
#pragma unroll
            for (int r = 0; r < 4; r++) {
                float e = (nt == 3 && inval3) ? 0.f : __expf(sv[nt][r] - mx[r]);
                sv[nt][r] = e;
                sm[r] += e;
            }
        }
#pragma unroll
        for (int d = 1; d < 16; d <<= 1) {
#pragma unroll
            for (int r = 0; r < 4; r++) sm[r] += __shfl_xor(sm[r], d);
        }
        float inv[4];
#pragma unroll
        for (int r = 0; r < 4; r++) inv[r] = 1.f / sm[r];
#pragma unroll
        for (int nt = 0; nt < 4; nt++) {
#pragma unroll
            for (int r = 0; r < 4; r++)
                ps[t0 + q4 + r][nt * 16 + l16] = f2s(sv[nt][r] * inv[r]);
        }
        __syncthreads();                            // ps ready
        short8 p0 = *(const short8*)&ps[t0 + l16][q8];
        short8 p1 = *(const short8*)&ps[t0 + l16][32 + q8];
#pragma unroll
        for (int nt = 0; nt < 2; nt++) {
            f32x4 acc = {0.f, 0.f, 0.f, 0.f};
            acc = MFMA(p0, *(const short8*)&vt[h * 32 + nt * 16 + l16][q8],      acc);
            acc = MFMA(p1, *(const short8*)&vt[h * 32 + nt * 16 + l16][32 + q8], acc);
            int d = nt * 16 + l16;
#pragma unroll
            for (int r = 0; r < 4; r++) {
                int t = t0 + q4 + r;
                if (t < 49) qk[t][h * 32 + d] = f2s(acc[r]);
            }
        }
    }

    // ---- proj + residual: single 96-wide chunk ----
    __syncthreads();
#pragma unroll
    for (int k = 0; k < 9; k++) {
        int i = tid + k * 256;
        int j = i / 24, qc = i - j * 24;
        f32x4 w4 = *(const f32x4*)&projw[j * 96 + qc * 4];
        s16x4 s4;
#pragma unroll
        for (int jj = 0; jj < 4; jj++) s4[jj] = f2s(w4[jj]);
        *(s16x4*)&wb[j][qc * 4] = s4;
    }
    __syncthreads();
    short8 o0 = *(const short8*)&qk[t0 + l16][q8];
    short8 o1 = *(const short8*)&qk[t0 + l16][32 + q8];
    short8 o2 = *(const short8*)&qk[t0 + l16][64 + q8];
    int  po[4];
    bool tv[4];
#pragma unroll
    for (int r = 0; r < 4; r++) {
        int t = t0 + q4 + r;
        tv[r] = (t < 49);
        int tt = tv[r] ? t : 0;
        int rr = tt / 7, cc = tt - rr * 7;
        int hh = wh * 7 + rr + 3;  if (hh >= D_H) hh -= D_H;
        int w2 = ww * 7 + cc + 3;  if (w2 >= D_W) w2 -= D_W;
        po[r] = (b * 96) * D_HW + hh * D_W + w2;
    }
#pragma unroll
    for (int nt = 0; nt < 6; nt++) {
        f32x4 acc = {0.f, 0.f, 0.f, 0.f};
        acc = MFMA(o0, *(const short8*)&wb[nt * 16 + l16][q8],      acc);
        acc = MFMA(o1, *(const short8*)&wb[nt * 16 + l16][32 + q8], acc);
        acc = MFMA(o2, *(const short8*)&wb[nt * 16 + l16][64 + q8], acc);
        int i = nt * 16 + l16;
        float pb = projb[i];
#pragma unroll
        for (int r = 0; r < 4; r++) {
            if (tv[r]) {
                int off = po[r] + i * D_HW;
                y[off] = x[off] + acc[r] + pb;
            }
        }
    }
}

// ---------------------------------------------------------------------------
// K2: MLP, 128 tokens/block (3136 blocks), float4 I/O + staging, parallel LN.
//   LDS ~74 KB -> 2 blocks/CU. In-place on y.
// ---------------------------------------------------------------------------
__global__ __launch_bounds__(256) void k_mlp(
    float* __restrict__ y, const float* __restrict__ n2g, const float* __restrict__ n2b,
    const float* __restrict__ w1, const float* __restrict__ b1,
    const float* __restrict__ w2, const float* __restrict__ b2)
{
    __shared__ short xs[128][104];   // normalized tokens; reused for epilogue
    __shared__ short wb[96][104];    // W1 or W2 chunk
    __shared__ short hb[128][104];   // GELU(H) chunk
    __shared__ float mean_s[128], rstd_s[128];

    const int tid  = threadIdx.x;
    const int wave = tid >> 6, lane = tid & 63;
    const int l16  = lane & 15, q8 = (lane >> 4) * 8, q4 = (lane >> 4) * 4;
    const int t0   = wave * 32;

    const int T0 = blockIdx.x * 128;           // 50176 % 128 == 0
    const int b  = T0 / D_HW;
    const int p0 = T0 - b * D_HW;
    const int base = (b * 96) * D_HW + p0;

    for (int idx = tid; idx < 96 * 32; idx += 256) {
        int c = idx >> 5, q = idx & 31;
        f32x4 v4 = *(const f32x4*)&y[base + c * D_HW + q * 4];
        xs[q * 4 + 0][c] = f2s(v4[0]);
        xs[q * 4 + 1][c] = f2s(v4[1]);
        xs[q * 4 + 2][c] = f2s(v4[2]);
        xs[q * 4 + 3][c] = f2s(v4[3]);
    }
    __syncthreads();
    {
        int t = tid >> 1, p = tid & 1;
        float s = 0.f, s2 = 0.f;
#pragma unroll
        for (int i = 0; i < 12; i++) {
            s16x4 v4 = *(const s16x4*)&xs[t][p * 48 + i * 4];
#pragma unroll
            for (int j = 0; j < 4; j++) { float v = s2f(v4[j]); s += v; s2 += v * v; }
        }
        s += __shfl_xor(s, 1); s2 += __shfl_xor(s2, 1);
        float m = s * (1.f / 96.f);
        float var = s2 * (1.f / 96.f) - m * m;
        mean_s[t] = m; rstd_s[t] = rsqrtf(var + 1e-5f);   // both lanes write same value
    }
    __syncthreads();
    for (int idx = tid; idx < 128 * 24; idx += 256) {
        int t = idx / 24, qc = idx - t * 24;
        s16x4 v4 = *(const s16x4*)&xs[t][qc * 4];
        f32x4 g  = *(const f32x4*)&n2g[qc * 4];
        f32x4 bb = *(const f32x4*)&n2b[qc * 4];
        float m = mean_s[t], rs = rstd_s[t];
#pragma unroll
        for (int j = 0; j < 4; j++) v4[j] = f2s((s2f(v4[j]) - m) * rs * g[j] + bb[j]);
        *(s16x4*)&xs[t][qc * 4] = v4;
    }
    __syncthreads();

    short8 xa[2][3];
#pragma unroll
    for (int s = 0; s < 2; s++)
#pragma unroll
        for (int kk = 0; kk < 3; kk++)
            xa[s][kk] = *(const short8*)&xs[t0 + s * 16 + l16][kk * 32 + q8];

    f32x4 c2[2][6];
#pragma unroll
    for (int s = 0; s < 2; s++)
#pragma unroll
        for (int nt = 0; nt < 6; nt++) c2[s][nt] = (f32x4){0.f, 0.f, 0.f, 0.f};

    for (int jc = 0; jc < 4; jc++) {
        // --- stage W1 chunk (float4), compute H = gelu(Xn W1c^T + b1) ---
        __syncthreads();
#pragma unroll
        for (int k = 0; k < 9; k++) {
            int i = tid + k * 256;                  // < 2304
            int j = i / 24, qc = i - j * 24;
            f32x4 w4 = *(const f32x4*)&w1[(jc * 96 + j) * 96 + qc * 4];
            s16x4 s4;
#pragma unroll
            for (int jj = 0; jj < 4; jj++) s4[jj] = f2s(w4[jj]);
            *(s16x4*)&wb[j][qc * 4] = s4;
        }
        __syncthreads();
#pragma unroll
        for (int s = 0; s < 2; s++) {
#pragma unroll
            for (int nt = 0; nt < 6; nt++) {
                f32x4 acc = {0.f, 0.f, 0.f, 0.f};
                acc = MFMA(xa[s][0], *(const short8*)&wb[nt * 16 + l16][q8],      acc);
                acc = MFMA(xa[s][1], *(const short8*)&wb[nt * 16 + l16][32 + q8], acc);
                acc = MFMA(xa[s][2], *(const short8*)&wb[nt * 16 + l16][64 + q8], acc);
                float bb = b1[jc * 96 + nt * 16 + l16];
#pragma unroll
                for (int r = 0; r < 4; r++) {
                    float v = acc[r] + bb;
                    float g = 0.5f * v * (1.f + erff(v * 0.7071067811865475f));
                    hb[t0 + s * 16 + q4 + r][nt * 16 + l16] = f2s(g);
                }
            }
        }
        // --- stage W2 chunk (float4), accumulate C2 += H W2c^T ---
        __syncthreads();
#pragma unroll
        for (int k = 0; k < 9; k++) {
            int i = tid + k * 256;
            int o = i / 24, qc = i - o * 24;
            f32x4 w4 = *(const f32x4*)&w2[o * 384 + jc * 96 + qc * 4];
            s16x4 s4;
#pragma unroll
            for (int jj = 0; jj < 4; jj++) s4[jj] = f2s(w4[jj]);
            *(s16x4*)&wb[o][qc * 4] = s4;
        }
        __syncthreads();
#pragma unroll
        for (int s = 0; s < 2; s++) {
            short8 h0 = *(const short8*)&hb[t0 + s * 16 + l16][q8];
            short8 h1 = *(const short8*)&hb[t0 + s * 16 + l16][32 + q8];
            short8 h2 = *(const short8*)&hb[t0 + s * 16 + l16][64 + q8];
#pragma unroll
            for (int nt = 0; nt < 6; nt++) {
                c2[s][nt] = MFMA(h0, *(const short8*)&wb[nt * 16 + l16][q8],      c2[s][nt]);
                c2[s][nt] = MFMA(h1, *(const short8*)&wb[nt * 16 + l16][32 + q8], c2[s][nt]);
                c2[s][nt] = MFMA(h2, *(const short8*)&wb[nt * 16 + l16][64 + q8], c2[s][nt]);
            }
        }
    }

    // --- epilogue through LDS for coalesced residual update ---
#pragma unroll
    for (int s = 0; s < 2; s++)
#pragma unroll
        for (int nt = 0; nt < 6; nt++) {
            int i = nt * 16 + l16;
            float bo = b2[i];
#pragma unroll
            for (int r = 0; r < 4; r++)
                xs[t0 + s * 16 + q4 + r][i] = f2s(bo + c2[s][nt][r]);
        }
    __syncthreads();
    for (int idx = tid; idx < 96 * 32; idx += 256) {
        int c = idx >> 5, q = idx & 31;
        int off = base + c * D_HW + q * 4;
        f32x4 v4 = *(const f32x4*)&y[off];
        v4[0] += s2f(xs[q * 4 + 0][c]);
        v4[1] += s2f(xs[q * 4 + 1][c]);
        v4[2] += s2f(xs[q * 4 + 2][c]);
        v4[3] += s2f(xs[q * 4 + 3][c]);
        *(f32x4*)&y[off] = v4;
    }
}

extern "C" void kernel_launch(void* const* d_in, const int* in_sizes, int n_in,
                              void* d_out, int out_size, void* d_ws, size_t ws_size,
                              hipStream_t stream) {
    const float* x    = (const float*)d_in[0];
    const float* n1g  = (const float*)d_in[1];
    const float* n1b  = (const float*)d_in[2];
    const float* qkvw = (const float*)d_in[3];
    const float* qkvb = (const float*)d_in[4];
    const float* relt = (const float*)d_in[5];
    const float* projw= (const float*)d_in[6];
    const float* projb= (const float*)d_in[7];
    const float* n2g  = (const float*)d_in[8];
    const float* n2b  = (const float*)d_in[9];
    const float* w1   = (const float*)d_in[10];
    const float* b1   = (const float*)d_in[11];
    const float* w2   = (const float*)d_in[12];
    const float* b2   = (const float*)d_in[13];
    float* y = (float*)d_out;

    k_attn<<<8192, 256, 0, stream>>>(x, n1g, n1b, qkvw, qkvb, relt, projw, projb, y);
    k_mlp<<<3136, 256, 0, stream>>>(y, n2g, n2b, w1, b1, w2, b2);
}